// Round 3
// baseline (137.799 us; speedup 1.0000x reference)
//
#include <hip/hip_runtime.h>
#include <stdint.h>

// MaskedMHSA: B=2 T=2048 E=768 H=12 DH=64
#define NROWS 4096      // B*T
#define EMB   768
#define NQKV  2304      // 3*E
#define TSEQ  2048
#define NHEAD 12
#define NBH   24        // B*H

typedef unsigned short u16;
typedef u16  ushort8 __attribute__((ext_vector_type(8)));
typedef __bf16 bf16x8 __attribute__((ext_vector_type(8)));
typedef float f32x4 __attribute__((ext_vector_type(4)));

typedef const __attribute__((address_space(1))) void* gas_ptr;
typedef __attribute__((address_space(3))) void* las_ptr;

__device__ __forceinline__ u16 f2bf(float f) {
  union { float f; uint32_t u; } v; v.f = f;
  uint32_t u = v.u;
  return (u16)((u + 0x7fffu + ((u >> 16) & 1u)) >> 16);
}
__device__ __forceinline__ uint32_t cvtpk(float lo, float hi) {
  uint32_t r;
  asm("v_cvt_pk_bf16_f32 %0, %1, %2" : "=v"(r) : "v"(lo), "v"(hi));
  return r;
}

#define VMCNT2 asm volatile("s_waitcnt vmcnt(2)" ::: "memory")
#define VMCNT0 asm volatile("s_waitcnt vmcnt(0)" ::: "memory")
#define LGKM0  asm volatile("s_waitcnt lgkmcnt(0)" ::: "memory")
#define SBAR   __builtin_amdgcn_s_barrier()
#define SCHED0 __builtin_amdgcn_sched_barrier(0)

// ---------------- pack kernels ----------------
__global__ __launch_bounds__(256) void k_pack_x(const float* __restrict__ x, u16* __restrict__ xb) {
  int i = (blockIdx.x * 256 + threadIdx.x) * 8;
  float4 a = *(const float4*)(x + i);
  float4 b = *(const float4*)(x + i + 4);
  uint4 o;
  o.x = cvtpk(a.x, a.y); o.y = cvtpk(a.z, a.w);
  o.z = cvtpk(b.x, b.y); o.w = cvtpk(b.z, b.w);
  *(uint4*)(xb + i) = o;
}

__global__ __launch_bounds__(256) void k_pack_wqkv(const float* __restrict__ Wq, const float* __restrict__ Wk,
                            const float* __restrict__ Wv, const float* __restrict__ bq,
                            const float* __restrict__ bk, const float* __restrict__ bv,
                            u16* __restrict__ wt, float* __restrict__ bias) {
  int idx = blockIdx.x * 256 + threadIdx.x;
  if (idx >= NQKV * EMB) return;
  int n = idx / EMB, e = idx - n * EMB;
  int sel = n / EMB;
  int c = n - sel * EMB;
  int h = c >> 6, d = c & 63;
  const float* W = sel == 0 ? Wq : (sel == 1 ? Wk : Wv);
  wt[idx] = f2bf(W[((size_t)h * EMB + e) * 64 + d]);
  if (e == 0) {
    const float* bs = sel == 0 ? bq : (sel == 1 ? bk : bv);
    bias[n] = bs[h * 64 + d];
  }
}

__global__ __launch_bounds__(256) void k_pack_wo(const float* __restrict__ Wo, u16* __restrict__ wot) {
  int idx = blockIdx.x * 256 + threadIdx.x;
  if (idx >= EMB * EMB) return;
  int n = idx / EMB, e = idx - n * EMB;
  wot[idx] = f2bf(Wo[(size_t)e * EMB + n]);
}

// ---------------- GEMM: C[M,N] = A[M,K] * Bt[N,K]^T + bias ----------------
template<int OUT_F32>
__global__ __launch_bounds__(256) void k_gemm(const u16* __restrict__ A, const u16* __restrict__ Bt,
                                              const float* __restrict__ bias, void* __restrict__ Cout,
                                              int M, int N, int K) {
  __shared__ u16 lds_a[128 * 32];
  __shared__ u16 lds_b[128 * 32];
  int tid = threadIdx.x;
  int w = tid >> 6, lane = tid & 63;
  int wr = w >> 1, wc = w & 1;
  int m0 = blockIdx.x * 128, n0 = blockIdx.y * 128;
  int lrow = lane & 15, lk8 = (lane >> 4) * 8;

  f32x4 zero = {0.f, 0.f, 0.f, 0.f};
  f32x4 acc[4][4];
  for (int m = 0; m < 4; ++m) for (int n = 0; n < 4; ++n) acc[m][n] = zero;

  int sr = tid >> 2;
  int sk = (tid & 3) * 8;

  for (int k0 = 0; k0 < K; k0 += 32) {
#pragma unroll
    for (int c = 0; c < 2; ++c) {
      int r = c * 64 + sr;
      const u16* ga = A  + (size_t)(m0 + r) * K + k0 + sk;
      const u16* gb = Bt + (size_t)(n0 + r) * K + k0 + sk;
      u16* la = lds_a + c * 2048 + w * 512;
      u16* lb = lds_b + c * 2048 + w * 512;
      __builtin_amdgcn_global_load_lds((gas_ptr)ga, (las_ptr)la, 16, 0, 0);
      __builtin_amdgcn_global_load_lds((gas_ptr)gb, (las_ptr)lb, 16, 0, 0);
    }
    __syncthreads();
    bf16x8 af[4], bfr[4];
#pragma unroll
    for (int m = 0; m < 4; ++m)
      af[m] = *(const bf16x8*)(lds_a + (wr * 64 + m * 16 + lrow) * 32 + lk8);
#pragma unroll
    for (int n = 0; n < 4; ++n)
      bfr[n] = *(const bf16x8*)(lds_b + (wc * 64 + n * 16 + lrow) * 32 + lk8);
#pragma unroll
    for (int m = 0; m < 4; ++m)
#pragma unroll
      for (int n = 0; n < 4; ++n)
        acc[m][n] = __builtin_amdgcn_mfma_f32_16x16x32_bf16(af[m], bfr[n], acc[m][n], 0, 0, 0);
    __syncthreads();
  }

#pragma unroll
  for (int m = 0; m < 4; ++m)
#pragma unroll
    for (int n = 0; n < 4; ++n) {
      int col = n0 + wc * 64 + n * 16 + lrow;
      float bcol = bias[col];
#pragma unroll
      for (int r = 0; r < 4; ++r) {
        int row = m0 + wr * 64 + m * 16 + (lane >> 4) * 4 + r;
        float v = acc[m][n][r] + bcol;
        if (OUT_F32) ((float*)Cout)[(size_t)row * N + col] = v;
        else         ((u16*)Cout)[(size_t)row * N + col] = f2bf(v);
      }
    }
}

// ---------------- V transpose: vt[bh][d][t] ----------------
__global__ __launch_bounds__(256) void k_transpose_v(const u16* __restrict__ qkv, u16* __restrict__ vt) {
  __shared__ u16 lds[64][65];
  int bh = blockIdx.y;
  int b = bh / NHEAD, h = bh - b * NHEAD;
  int t0 = blockIdx.x * 64;
  int tid = threadIdx.x;
  int r = tid >> 2, c0 = (tid & 3) * 16;
  const u16* src = qkv + (size_t)(b * TSEQ + t0 + r) * NQKV + 2 * EMB + h * 64 + c0;
  ushort8 v0 = *(const ushort8*)(src);
  ushort8 v1 = *(const ushort8*)(src + 8);
#pragma unroll
  for (int j = 0; j < 8; ++j) { lds[r][c0 + j] = v0[j]; lds[r][c0 + 8 + j] = v1[j]; }
  __syncthreads();
  int d = tid >> 2, tt = (tid & 3) * 16;
  ushort8 o0, o1;
#pragma unroll
  for (int j = 0; j < 8; ++j) { o0[j] = lds[tt + j][d]; o1[j] = lds[tt + 8 + j][d]; }
  u16* dst = vt + (size_t)(bh * 64 + d) * TSEQ + t0 + tt;
  *(ushort8*)dst = o0;
  *(ushort8*)(dst + 8) = o1;
}

// ---------------- causal flash attention ----------------
// grid (768): bid -> xcd=bid&7, slot=bid>>3; y=3*xcd+slot/32 (XCD-local K/V),
// qblk=31-(slot&31) (longest first; co-resident triples share qblk -> equal
// duration -> overlap persists). Fixed-max softmax (m=2.0 in log2 domain),
// deferred l-reduce, K 3-buf (2 ahead), V 2-buf (1 ahead), 1 barrier/tile,
// steady-state vmcnt(2).
__global__ __launch_bounds__(256) void k_attn(const u16* __restrict__ qkv, const u16* __restrict__ vt,
                                              u16* __restrict__ aout) {
  __shared__ u16 kbuf[3][64 * 64];
  __shared__ u16 vbuf[2][64 * 64];
  __shared__ u16 pbuf[4][16 * 64];
  int tid = threadIdx.x;
  int w = tid >> 6, lane = tid & 63;
  int ql = lane & 15, g = lane >> 4;
  int bid = blockIdx.x;
  int xcd = bid & 7, slot = bid >> 3;
  int y = xcd * 3 + (slot >> 5);
  int qblk = 31 - (slot & 31);
  int b = y / NHEAD, h = y - b * NHEAD;
  int nt = qblk + 1;
  int qrow0w = qblk * 64 + w * 16;
  int qg = qrow0w + ql;

  // Q fragments (B-operand: col=lane&15=q, k=8g+j)
  const u16* qp = qkv + (size_t)(b * TSEQ + qg) * NQKV + h * 64;
  bf16x8 bq0 = *(const bf16x8*)(qp + g * 8);
  bf16x8 bq1 = *(const bf16x8*)(qp + 32 + g * 8);

  const u16* kst = qkv + (size_t)(b * TSEQ) * NQKV + EMB + h * 64;
  const u16* vst = vt + (size_t)y * 64 * TSEQ;
  int srow = tid >> 3, scol = tid & 7;

  f32x4 zero = {0.f, 0.f, 0.f, 0.f};
  f32x4 o[4]; for (int n = 0; n < 4; ++n) o[n] = zero;
  float lr = 0.f;
  const float sc2 = 0.18033688f;  // (1/8) * log2(e)
  u16* pw = &pbuf[w][0];
  int swz = (ql & 7) << 3;

  auto STAGE_K = [&](int bi, int t_) {
#pragma unroll
    for (int i = 0; i < 2; ++i) {
      int row = i * 32 + srow;
      int c16 = scol ^ (row & 7);
      const u16* gk = kst + (size_t)(t_ * 64 + row) * NQKV + c16 * 8;
      __builtin_amdgcn_global_load_lds((gas_ptr)gk, (las_ptr)(&kbuf[bi][i * 2048 + w * 512]), 16, 0, 0);
    }
  };
  auto STAGE_V = [&](int bi, int t_) {
#pragma unroll
    for (int i = 0; i < 2; ++i) {
      int row = i * 32 + srow;
      int c16 = scol ^ (row & 7);
      const u16* gv = vst + (size_t)row * TSEQ + t_ * 64 + c16 * 8;
      __builtin_amdgcn_global_load_lds((gas_ptr)gv, (las_ptr)(&vbuf[bi][i * 2048 + w * 512]), 16, 0, 0);
    }
  };

  // prologue: queue order [V0, K0, K1]
  STAGE_V(0, 0);
  STAGE_K(0, 0);
  if (nt > 1) STAGE_K(1, 1);

  for (int t = 0; t < nt; ++t) {
    // need V(t),K(t) done; K(t+1) (if issued) may remain in flight
    if (t + 1 < nt) VMCNT2; else VMCNT0;
    SBAR;
    // issue after barrier: all waves are done reading the buffers we overwrite
    if (t + 1 < nt) STAGE_V((t + 1) & 1, t + 1);
    if (t + 2 < nt) STAGE_K((t + 2) % 3, t + 2);

    const u16* kb = &kbuf[t % 3][0];
    const u16* vb = &vbuf[t & 1][0];
    int s0 = t * 64;

    // QK^T swapped: lane holds S^T[s = s0+sblk*16+4g+r][q = qg]
    f32x4 st[4];
#pragma unroll
    for (int sblk = 0; sblk < 4; ++sblk) {
      int row = sblk * 16 + ql;
      bf16x8 ka0 = *(const bf16x8*)(kb + ((row * 64 + 8 * g) ^ swz));
      bf16x8 ka1 = *(const bf16x8*)(kb + ((row * 64 + 32 + 8 * g) ^ swz));
      f32x4 acc = zero;
      acc = __builtin_amdgcn_mfma_f32_16x16x32_bf16(ka0, bq0, acc, 0, 0, 0);
      acc = __builtin_amdgcn_mfma_f32_16x16x32_bf16(ka1, bq1, acc, 0, 0, 0);
      st[sblk] = acc;
    }

    // fixed-max softmax: e = exp2(S*sc2 - 2.0); mask only on last tile
    bool lastt = (t == nt - 1);
    float e[4][4];
#pragma unroll
    for (int sblk = 0; sblk < 4; ++sblk)
#pragma unroll
      for (int r = 0; r < 4; ++r) {
        float vv = __builtin_fmaf(st[sblk][r], sc2, -2.0f);
        if (lastt) {
          int sg = s0 + sblk * 16 + 4 * g + r;
          if (sg > qg) vv = -1e30f;
        }
        float ee = __builtin_amdgcn_exp2f(vv);
        e[sblk][r] = ee;
        lr += ee;
      }

    // P^T -> per-wave LDS [q][s] (swizzled), read back as PV A-fragments
#pragma unroll
    for (int sblk = 0; sblk < 4; ++sblk) {
      uint2 dw;
      dw.x = cvtpk(e[sblk][0], e[sblk][1]);
      dw.y = cvtpk(e[sblk][2], e[sblk][3]);
      *(uint2*)(pw + ((ql * 64 + sblk * 16 + 4 * g) ^ swz)) = dw;
    }
    LGKM0; SCHED0;
    bf16x8 ap0 = *(const bf16x8*)(pw + ((ql * 64 + 8 * g) ^ swz));
    bf16x8 ap1 = *(const bf16x8*)(pw + ((ql * 64 + 32 + 8 * g) ^ swz));

    // PV: O[q][d] += P[q][s] * Vt[d][s]
#pragma unroll
    for (int n = 0; n < 4; ++n) {
      int row = n * 16 + ql;
      bf16x8 vb0 = *(const bf16x8*)(vb + ((row * 64 + 8 * g) ^ swz));
      bf16x8 vb1 = *(const bf16x8*)(vb + ((row * 64 + 32 + 8 * g) ^ swz));
      o[n] = __builtin_amdgcn_mfma_f32_16x16x32_bf16(ap0, vb0, o[n], 0, 0, 0);
      o[n] = __builtin_amdgcn_mfma_f32_16x16x32_bf16(ap1, vb1, o[n], 0, 0, 0);
    }
  }

  // deferred l reduce: lane partial -> full row sum for q=ql
  lr += __shfl_xor(lr, 16);
  lr += __shfl_xor(lr, 32);
  float linv = 1.0f / lr;
  float li[4];
#pragma unroll
  for (int r = 0; r < 4; ++r) li[r] = __shfl(linv, 4 * g + r);
#pragma unroll
  for (int n = 0; n < 4; ++n)
#pragma unroll
    for (int r = 0; r < 4; ++r) {
      int q = qrow0w + 4 * g + r;
      aout[(size_t)(b * TSEQ + q) * EMB + h * 64 + n * 16 + ql] = f2bf(o[n][r] * li[r]);
    }
}

// ---------------- LayerNorm + residual ----------------
__global__ __launch_bounds__(256) void k_ln_res(const float* __restrict__ proj, const float* __restrict__ x,
                                                const float* __restrict__ gamma, const float* __restrict__ beta,
                                                float* __restrict__ out) {
  __shared__ float smem[2][4];
  int row = blockIdx.x;
  const float* pr = proj + (size_t)row * EMB;
  const float* xr = x + (size_t)row * EMB;
  float* orow = out + (size_t)row * EMB;
  int tid = threadIdx.x;
  float v[3];
  float s = 0.f, s2 = 0.f;
#pragma unroll
  for (int i = 0; i < 3; ++i) { v[i] = pr[tid + 256 * i]; s += v[i]; s2 += v[i] * v[i]; }
#pragma unroll
  for (int m = 1; m < 64; m <<= 1) { s += __shfl_xor(s, m); s2 += __shfl_xor(s2, m); }
  int w = tid >> 6, lane = tid & 63;
  if (lane == 0) { smem[0][w] = s; smem[1][w] = s2; }
  __syncthreads();
  s  = smem[0][0] + smem[0][1] + smem[0][2] + smem[0][3];
  s2 = smem[1][0] + smem[1][1] + smem[1][2] + smem[1][3];
  float mu = s * (1.f / EMB);
  float var = s2 * (1.f / EMB) - mu * mu;
  float rstd = rsqrtf(var + 1e-5f);
#pragma unroll
  for (int i = 0; i < 3; ++i) {
    int c = tid + 256 * i;
    orow[c] = xr[c] + (v[i] - mu) * rstd * gamma[c] + beta[c];
  }
}

// ---------------- launch ----------------
extern "C" void kernel_launch(void* const* d_in, const int* in_sizes, int n_in,
                              void* d_out, int out_size, void* d_ws, size_t ws_size,
                              hipStream_t stream) {
  const float* x     = (const float*)d_in[0];
  const float* Wq    = (const float*)d_in[1];
  const float* bq    = (const float*)d_in[2];
  const float* Wk    = (const float*)d_in[3];
  const float* bk    = (const float*)d_in[4];
  const float* Wv    = (const float*)d_in[5];
  const float* bv    = (const float*)d_in[6];
  const float* Wo    = (const float*)d_in[7];
  const float* bo    = (const float*)d_in[8];
  const float* gamma = (const float*)d_in[9];
  const float* beta  = (const float*)d_in[10];
  float* out = (float*)d_out;

  char* ws = (char*)d_ws;
  size_t off = 0;
  u16* xb    = (u16*)(ws + off); off += (size_t)NROWS * EMB * 2;
  u16* wqkvt = (u16*)(ws + off); off += (size_t)NQKV * EMB * 2;
  u16* wot   = (u16*)(ws + off); off += (size_t)EMB * EMB * 2;
  float* bqkv = (float*)(ws + off); off += (size_t)NQKV * 4;
  u16* qkv   = (u16*)(ws + off); off += (size_t)NROWS * NQKV * 2;
  u16* vt    = (u16*)(ws + off); off += (size_t)NBH * 64 * TSEQ * 2;
  u16* aout  = (u16*)(ws + off); off += (size_t)NROWS * EMB * 2;
  float* proj = (float*)qkv;  // alias: qkv dead after attention

  k_pack_x<<<NROWS * EMB / (256 * 8), 256, 0, stream>>>(x, xb);
  k_pack_wqkv<<<(NQKV * EMB + 255) / 256, 256, 0, stream>>>(Wq, Wk, Wv, bq, bk, bv, wqkvt, bqkv);
  k_pack_wo<<<(EMB * EMB + 255) / 256, 256, 0, stream>>>(Wo, wot);
  k_gemm<0><<<dim3(NROWS / 128, NQKV / 128), 256, 0, stream>>>(xb, wqkvt, bqkv, qkv, NROWS, NQKV, EMB);
  k_transpose_v<<<dim3(TSEQ / 64, NBH), 256, 0, stream>>>(qkv, vt);
  k_attn<<<dim3(768), 256, 0, stream>>>(qkv, vt, aout);
  k_gemm<1><<<dim3(NROWS / 128, EMB / 128), 256, 0, stream>>>(aout, wot, bo, proj, NROWS, EMB, EMB);
  k_ln_res<<<NROWS, 256, 0, stream>>>(proj, x, gamma, beta, out);
}

// Round 4
// 134.942 us; speedup vs baseline: 1.0212x; 1.0212x over previous
//
#include <hip/hip_runtime.h>
#include <stdint.h>

// MaskedMHSA: B=2 T=2048 E=768 H=12 DH=64
#define NROWS 4096      // B*T
#define EMB   768
#define NQKV  2304      // 3*E
#define TSEQ  2048
#define NHEAD 12
#define NBH   24        // B*H

typedef unsigned short u16;
typedef u16  ushort4v __attribute__((ext_vector_type(4)));
typedef u16  ushort8 __attribute__((ext_vector_type(8)));
typedef __bf16 bf16x8 __attribute__((ext_vector_type(8)));
typedef float f32x4 __attribute__((ext_vector_type(4)));

typedef const __attribute__((address_space(1))) void* gas_ptr;
typedef __attribute__((address_space(3))) void* las_ptr;

__device__ __forceinline__ u16 f2bf(float f) {
  union { float f; uint32_t u; } v; v.f = f;
  uint32_t u = v.u;
  return (u16)((u + 0x7fffu + ((u >> 16) & 1u)) >> 16);
}
__device__ __forceinline__ uint32_t cvtpk(float lo, float hi) {
  uint32_t r;
  asm("v_cvt_pk_bf16_f32 %0, %1, %2" : "=v"(r) : "v"(lo), "v"(hi));
  return r;
}

#define VMCNT0 asm volatile("s_waitcnt vmcnt(0)" ::: "memory")
#define LGKM0  asm volatile("s_waitcnt lgkmcnt(0)" ::: "memory")
#define SBAR   __builtin_amdgcn_s_barrier()
#define SCHED0 __builtin_amdgcn_sched_barrier(0)

// ---------------- init: zero the 8 per-XCD task counters ----------------
__global__ void k_zero(uint32_t* cnt) {
  if (threadIdx.x < 8) cnt[threadIdx.x] = 0;
}

// ---------------- pack kernels ----------------
__global__ __launch_bounds__(256) void k_pack_x(const float* __restrict__ x, u16* __restrict__ xb) {
  int i = (blockIdx.x * 256 + threadIdx.x) * 8;
  float4 a = *(const float4*)(x + i);
  float4 b = *(const float4*)(x + i + 4);
  uint4 o;
  o.x = cvtpk(a.x, a.y); o.y = cvtpk(a.z, a.w);
  o.z = cvtpk(b.x, b.y); o.w = cvtpk(b.z, b.w);
  *(uint4*)(xb + i) = o;
}

__global__ __launch_bounds__(256) void k_pack_wqkv(const float* __restrict__ Wq, const float* __restrict__ Wk,
                            const float* __restrict__ Wv, const float* __restrict__ bq,
                            const float* __restrict__ bk, const float* __restrict__ bv,
                            u16* __restrict__ wt, float* __restrict__ bias) {
  int idx = blockIdx.x * 256 + threadIdx.x;
  if (idx >= NQKV * EMB) return;
  int n = idx / EMB, e = idx - n * EMB;
  int sel = n / EMB;
  int c = n - sel * EMB;
  int h = c >> 6, d = c & 63;
  const float* W = sel == 0 ? Wq : (sel == 1 ? Wk : Wv);
  wt[idx] = f2bf(W[((size_t)h * EMB + e) * 64 + d]);
  if (e == 0) {
    const float* bs = sel == 0 ? bq : (sel == 1 ? bk : bv);
    bias[n] = bs[h * 64 + d];
  }
}

__global__ __launch_bounds__(256) void k_pack_wo(const float* __restrict__ Wo, u16* __restrict__ wot) {
  int idx = blockIdx.x * 256 + threadIdx.x;
  if (idx >= EMB * EMB) return;
  int n = idx / EMB, e = idx - n * EMB;
  wot[idx] = f2bf(Wo[(size_t)e * EMB + n]);
}

// ---------------- GEMM: C[M,N] = A[M,K] * Bt[N,K]^T + bias ----------------
// BK=64, XOR-swizzled LDS (stage via pre-swizzled global col), 2x2 waves.
// OUT_MODE: 0 = bf16 out, 1 = f32 out, 2 = bf16 qkv + V-region transposed to vt[d][t]
template<int BM, int BN, int OUT_MODE>
__global__ __launch_bounds__(256) void k_gemm(const u16* __restrict__ A, const u16* __restrict__ Bt,
                                              const float* __restrict__ bias, void* __restrict__ Cout,
                                              u16* __restrict__ vtout, int M, int N, int K) {
  constexpr int MR = BM / 32, NR = BN / 32;
  __shared__ u16 lds_a[BM * 64];
  __shared__ u16 lds_b[BN * 64];
  int tid = threadIdx.x;
  int w = tid >> 6, lane = tid & 63;
  int wr = w >> 1, wc = w & 1;
  int m0 = blockIdx.x * BM, n0 = blockIdx.y * BN;
  int lrow = lane & 15, g = lane >> 4;

  f32x4 zero = {0.f, 0.f, 0.f, 0.f};
  f32x4 acc[MR][NR];
  for (int m = 0; m < MR; ++m) for (int n = 0; n < NR; ++n) acc[m][n] = zero;

  int l8 = lane >> 3, c8 = lane & 7;

  for (int k0 = 0; k0 < K; k0 += 64) {
    // stage A (BM x 64) and B (BN x 64), swizzled source col
#pragma unroll
    for (int i = 0; i < BM / 32; ++i) {
      int row = w * (BM / 4) + 8 * i + l8;
      int c16 = c8 ^ (row & 7);
      const u16* ga = A + (size_t)(m0 + row) * K + k0 + c16 * 8;
      __builtin_amdgcn_global_load_lds((gas_ptr)ga, (las_ptr)(lds_a + (w * (BM / 4) + 8 * i) * 64), 16, 0, 0);
    }
#pragma unroll
    for (int i = 0; i < BN / 32; ++i) {
      int row = w * (BN / 4) + 8 * i + l8;
      int c16 = c8 ^ (row & 7);
      const u16* gb = Bt + (size_t)(n0 + row) * K + k0 + c16 * 8;
      __builtin_amdgcn_global_load_lds((gas_ptr)gb, (las_ptr)(lds_b + (w * (BN / 4) + 8 * i) * 64), 16, 0, 0);
    }
    __syncthreads();
    bf16x8 af[MR][2], bfr[NR][2];
#pragma unroll
    for (int m = 0; m < MR; ++m)
#pragma unroll
      for (int kc = 0; kc < 2; ++kc) {
        int row = wr * (BM / 2) + m * 16 + lrow;
        int ch = (kc * 4 + g) ^ (row & 7);
        af[m][kc] = *(const bf16x8*)(lds_a + row * 64 + ch * 8);
      }
#pragma unroll
    for (int n = 0; n < NR; ++n)
#pragma unroll
      for (int kc = 0; kc < 2; ++kc) {
        int row = wc * (BN / 2) + n * 16 + lrow;
        int ch = (kc * 4 + g) ^ (row & 7);
        bfr[n][kc] = *(const bf16x8*)(lds_b + row * 64 + ch * 8);
      }
#pragma unroll
    for (int kc = 0; kc < 2; ++kc)
#pragma unroll
      for (int m = 0; m < MR; ++m)
#pragma unroll
        for (int n = 0; n < NR; ++n)
          acc[m][n] = __builtin_amdgcn_mfma_f32_16x16x32_bf16(af[m][kc], bfr[n][kc], acc[m][n], 0, 0, 0);
    __syncthreads();
  }

#pragma unroll
  for (int m = 0; m < MR; ++m)
#pragma unroll
    for (int n = 0; n < NR; ++n) {
      int col = n0 + wc * (BN / 2) + n * 16 + lrow;
      float bcol = bias[col];
      int row0 = m0 + wr * (BM / 2) + m * 16 + 4 * g;
      if (OUT_MODE == 2 && col >= 2 * EMB) {
        // V region -> vt[(y*64+d)][t], t = row0..row0+3 contiguous
        int c = col - 2 * EMB;
        int hh = c >> 6, d = c & 63;
        int bb = row0 >> 11, t = row0 & 2047;
        int y = bb * NHEAD + hh;
        ushort4v pk;
#pragma unroll
        for (int r = 0; r < 4; ++r) pk[r] = f2bf(acc[m][n][r] + bcol);
        *(ushort4v*)(vtout + (size_t)(y * 64 + d) * TSEQ + t) = pk;
      } else {
#pragma unroll
        for (int r = 0; r < 4; ++r) {
          int row = row0 + r;
          float v = acc[m][n][r] + bcol;
          if (OUT_MODE == 1) ((float*)Cout)[(size_t)row * N + col] = v;
          else               ((u16*)Cout)[(size_t)row * N + col] = f2bf(v);
        }
      }
    }
}

// ---------------- causal flash attention: persistent + per-XCD queues ----------------
// Task = (y, qb): 64 q-rows of head-batch y, duration qb+1 K-tiles, pulled in
// descending-duration order from this XCD's queue (96 tasks each). 4 waves per
// block (16 q-rows each) share double-buffered K/V LDS; 1 barrier + 1 vmcnt(0)
// per tile; fixed-max softmax (exp2 domain), deferred l-reduce.
__global__ __launch_bounds__(256, 4) void k_attn(const u16* __restrict__ qkv, const u16* __restrict__ vt,
                                                 u16* __restrict__ aout, uint32_t* __restrict__ cnt) {
  __shared__ u16 kbuf[2][64 * 64];
  __shared__ u16 vbuf[2][64 * 64];
  __shared__ u16 pbuf[4][16 * 64];
  __shared__ int task_s;
  int tid = threadIdx.x;
  int w = tid >> 6, lane = tid & 63;
  int ql = lane & 15, g = lane >> 4;
  int xcd = blockIdx.x & 7;
  const float sc2 = 0.18033688f;  // (1/8) * log2(e)
  u16* pw = &pbuf[w][0];
  int swz = (ql & 7) << 3;
  int l8 = lane >> 3, c8 = lane & 7;

  for (;;) {
    if (tid == 0) task_s = (int)atomicAdd(&cnt[xcd], 1u);
    __syncthreads();
    int tau = task_s;
    __syncthreads();
    if (tau >= 96) break;

    int idx = tau / 3;
    int yl = tau - idx * 3;
    int qb = 31 - idx;               // descending duration
    int y = xcd * 3 + yl;
    int b = y / NHEAD, h = y - b * NHEAD;
    int nt = qb + 1;
    int qrow0w = qb * 64 + w * 16;
    int qg = qrow0w + ql;

    // Q fragments (B-operand: col=lane&15=q, k=8g+j)
    const u16* qp = qkv + (size_t)(b * TSEQ + qg) * NQKV + h * 64;
    bf16x8 bq0 = *(const bf16x8*)(qp + g * 8);
    bf16x8 bq1 = *(const bf16x8*)(qp + 32 + g * 8);

    const u16* kst = qkv + (size_t)(b * TSEQ) * NQKV + EMB + h * 64;
    const u16* vst = vt + (size_t)y * 64 * TSEQ;

    f32x4 zero = {0.f, 0.f, 0.f, 0.f};
    f32x4 o[4]; for (int n = 0; n < 4; ++n) o[n] = zero;
    float lr = 0.f;

    auto STAGE = [&](int bi, int t_) {
#pragma unroll
      for (int i = 0; i < 2; ++i) {
        int row = i * 32 + 8 * w + l8;
        int c16 = c8 ^ (row & 7);
        const u16* gk = kst + (size_t)(t_ * 64 + row) * NQKV + c16 * 8;
        __builtin_amdgcn_global_load_lds((gas_ptr)gk, (las_ptr)(&kbuf[bi][(i * 32 + 8 * w) * 64]), 16, 0, 0);
        const u16* gv = vst + (size_t)row * TSEQ + t_ * 64 + c16 * 8;
        __builtin_amdgcn_global_load_lds((gas_ptr)gv, (las_ptr)(&vbuf[bi][(i * 32 + 8 * w) * 64]), 16, 0, 0);
      }
    };

    STAGE(0, 0);
    for (int t = 0; t < nt; ++t) {
      int cur = t & 1;
      VMCNT0;
      SBAR;
      if (t + 1 < nt) STAGE(cur ^ 1, t + 1);

      const u16* kb = &kbuf[cur][0];
      const u16* vb = &vbuf[cur][0];
      int s0 = t * 64;

      // QK^T swapped: lane holds S^T[s = s0+sblk*16+4g+r][q = qg]
      f32x4 st[4];
#pragma unroll
      for (int sblk = 0; sblk < 4; ++sblk) {
        int row = sblk * 16 + ql;
        bf16x8 ka0 = *(const bf16x8*)(kb + ((row * 64 + 8 * g) ^ swz));
        bf16x8 ka1 = *(const bf16x8*)(kb + ((row * 64 + 32 + 8 * g) ^ swz));
        f32x4 acc = zero;
        acc = __builtin_amdgcn_mfma_f32_16x16x32_bf16(ka0, bq0, acc, 0, 0, 0);
        acc = __builtin_amdgcn_mfma_f32_16x16x32_bf16(ka1, bq1, acc, 0, 0, 0);
        st[sblk] = acc;
      }

      // fixed-max softmax: e = exp2(S*sc2 - 2.0); mask only on last tile
      bool lastt = (t == nt - 1);
      float e[4][4];
#pragma unroll
      for (int sblk = 0; sblk < 4; ++sblk)
#pragma unroll
        for (int r = 0; r < 4; ++r) {
          float vv = __builtin_fmaf(st[sblk][r], sc2, -2.0f);
          if (lastt) {
            int sg = s0 + sblk * 16 + 4 * g + r;
            if (sg > qg) vv = -1e30f;
          }
          float ee = __builtin_amdgcn_exp2f(vv);
          e[sblk][r] = ee;
          lr += ee;
        }

      // P^T -> per-wave LDS [q][s] (swizzled), read back as PV A-fragments
#pragma unroll
      for (int sblk = 0; sblk < 4; ++sblk) {
        uint2 dw;
        dw.x = cvtpk(e[sblk][0], e[sblk][1]);
        dw.y = cvtpk(e[sblk][2], e[sblk][3]);
        *(uint2*)(pw + ((ql * 64 + sblk * 16 + 4 * g) ^ swz)) = dw;
      }
      LGKM0; SCHED0;
      bf16x8 ap0 = *(const bf16x8*)(pw + ((ql * 64 + 8 * g) ^ swz));
      bf16x8 ap1 = *(const bf16x8*)(pw + ((ql * 64 + 32 + 8 * g) ^ swz));

      // PV: O[q][d] += P[q][s] * Vt[d][s]
#pragma unroll
      for (int n = 0; n < 4; ++n) {
        int row = n * 16 + ql;
        bf16x8 vb0 = *(const bf16x8*)(vb + ((row * 64 + 8 * g) ^ swz));
        bf16x8 vb1 = *(const bf16x8*)(vb + ((row * 64 + 32 + 8 * g) ^ swz));
        o[n] = __builtin_amdgcn_mfma_f32_16x16x32_bf16(ap0, vb0, o[n], 0, 0, 0);
        o[n] = __builtin_amdgcn_mfma_f32_16x16x32_bf16(ap1, vb1, o[n], 0, 0, 0);
      }
    }

    // deferred l reduce: lane partial -> full row sum for q=ql
    float lw = lr;
    lw += __shfl_xor(lw, 16);
    lw += __shfl_xor(lw, 32);
    float linv = 1.0f / lw;
    float li[4];
#pragma unroll
    for (int r = 0; r < 4; ++r) li[r] = __shfl(linv, 4 * g + r);
#pragma unroll
    for (int n = 0; n < 4; ++n)
#pragma unroll
      for (int r = 0; r < 4; ++r) {
        int q = qrow0w + 4 * g + r;
        aout[(size_t)(b * TSEQ + q) * EMB + h * 64 + n * 16 + ql] = f2bf(o[n][r] * li[r]);
      }
  }
}

// ---------------- LayerNorm + residual ----------------
__global__ __launch_bounds__(256) void k_ln_res(const float* __restrict__ proj, const float* __restrict__ x,
                                                const float* __restrict__ gamma, const float* __restrict__ beta,
                                                float* __restrict__ out) {
  __shared__ float smem[2][4];
  int row = blockIdx.x;
  const float* pr = proj + (size_t)row * EMB;
  const float* xr = x + (size_t)row * EMB;
  float* orow = out + (size_t)row * EMB;
  int tid = threadIdx.x;
  float v[3];
  float s = 0.f, s2 = 0.f;
#pragma unroll
  for (int i = 0; i < 3; ++i) { v[i] = pr[tid + 256 * i]; s += v[i]; s2 += v[i] * v[i]; }
#pragma unroll
  for (int m = 1; m < 64; m <<= 1) { s += __shfl_xor(s, m); s2 += __shfl_xor(s2, m); }
  int w = tid >> 6, lane = tid & 63;
  if (lane == 0) { smem[0][w] = s; smem[1][w] = s2; }
  __syncthreads();
  s  = smem[0][0] + smem[0][1] + smem[0][2] + smem[0][3];
  s2 = smem[1][0] + smem[1][1] + smem[1][2] + smem[1][3];
  float mu = s * (1.f / EMB);
  float var = s2 * (1.f / EMB) - mu * mu;
  float rstd = rsqrtf(var + 1e-5f);
#pragma unroll
  for (int i = 0; i < 3; ++i) {
    int c = tid + 256 * i;
    orow[c] = xr[c] + (v[i] - mu) * rstd * gamma[c] + beta[c];
  }
}

// ---------------- launch ----------------
extern "C" void kernel_launch(void* const* d_in, const int* in_sizes, int n_in,
                              void* d_out, int out_size, void* d_ws, size_t ws_size,
                              hipStream_t stream) {
  const float* x     = (const float*)d_in[0];
  const float* Wq    = (const float*)d_in[1];
  const float* bq    = (const float*)d_in[2];
  const float* Wk    = (const float*)d_in[3];
  const float* bk    = (const float*)d_in[4];
  const float* Wv    = (const float*)d_in[5];
  const float* bv    = (const float*)d_in[6];
  const float* Wo    = (const float*)d_in[7];
  const float* bo    = (const float*)d_in[8];
  const float* gamma = (const float*)d_in[9];
  const float* beta  = (const float*)d_in[10];
  float* out = (float*)d_out;

  char* ws = (char*)d_ws;
  size_t off = 0;
  u16* xb    = (u16*)(ws + off); off += (size_t)NROWS * EMB * 2;
  u16* wqkvt = (u16*)(ws + off); off += (size_t)NQKV * EMB * 2;
  u16* wot   = (u16*)(ws + off); off += (size_t)EMB * EMB * 2;
  float* bqkv = (float*)(ws + off); off += (size_t)NQKV * 4;
  uint32_t* cnt = (uint32_t*)(ws + off); off += 64;
  u16* qkv   = (u16*)(ws + off); off += (size_t)NROWS * NQKV * 2;
  u16* vt    = (u16*)(ws + off); off += (size_t)NBH * 64 * TSEQ * 2;
  u16* aout  = (u16*)(ws + off); off += (size_t)NROWS * EMB * 2;
  float* proj = (float*)qkv;  // alias: qkv dead after attention

  k_zero<<<1, 64, 0, stream>>>(cnt);
  k_pack_x<<<NROWS * EMB / (256 * 8), 256, 0, stream>>>(x, xb);
  k_pack_wqkv<<<(NQKV * EMB + 255) / 256, 256, 0, stream>>>(Wq, Wk, Wv, bq, bk, bv, wqkvt, bqkv);
  k_pack_wo<<<(EMB * EMB + 255) / 256, 256, 0, stream>>>(Wo, wot);
  k_gemm<128, 128, 2><<<dim3(NROWS / 128, NQKV / 128), 256, 0, stream>>>(xb, wqkvt, bqkv, qkv, vt, NROWS, NQKV, EMB);
  k_attn<<<dim3(1024), 256, 0, stream>>>(qkv, vt, aout, cnt);
  k_gemm<128, 64, 1><<<dim3(NROWS / 128, EMB / 64), 256, 0, stream>>>(aout, wot, bo, proj, nullptr, NROWS, EMB, EMB);
  k_ln_res<<<NROWS, 256, 0, stream>>>(proj, x, gamma, beta, out);
}